// Round 4
// baseline (1214.764 us; speedup 1.0000x reference)
//
#include <hip/hip_runtime.h>
#include <stdint.h>

#define TOKENS 8192
#define HIDDEN 1024
#define INTER  2816
#define NEXP   8

typedef float floatx4 __attribute__((ext_vector_type(4)));
typedef __bf16 bf16x8 __attribute__((ext_vector_type(8)));

__device__ __forceinline__ unsigned short f2bf(float f) {
  unsigned int u = __float_as_uint(f);
  u += 0x7fffu + ((u >> 16) & 1u);
  return (unsigned short)(u >> 16);
}

__device__ __forceinline__ void async16(const void* g, void* l) {
  __builtin_amdgcn_global_load_lds(
      (const __attribute__((address_space(1))) void*)g,
      (__attribute__((address_space(3))) void*)l, 16, 0, 0);
}

// ---------------- fp32 -> bf16 conversion (4 tensors, one launch) ----------------
__global__ void cvt_bf16_4(const float* __restrict__ s0, unsigned short* __restrict__ d0, int n0,
                           const float* __restrict__ s1, unsigned short* __restrict__ d1, int n1,
                           const float* __restrict__ s2, unsigned short* __restrict__ d2, int n2,
                           const float* __restrict__ s3, unsigned short* __restrict__ d3, int n3) {
  const float* s; unsigned short* d; int n;
  switch (blockIdx.z) {
    case 0: s = s0; d = d0; n = n0; break;
    case 1: s = s1; d = d1; n = n1; break;
    case 2: s = s2; d = d2; n = n2; break;
    default: s = s3; d = d3; n = n3; break;
  }
  int i = blockIdx.x * blockDim.x + threadIdx.x;
  int stride = gridDim.x * blockDim.x;
  for (; i < n; i += stride) {
    float4 v = ((const float4*)s)[i];
    ushort4 o;
    o.x = f2bf(v.x); o.y = f2bf(v.y); o.z = f2bf(v.z); o.w = f2bf(v.w);
    ((ushort4*)d)[i] = o;
  }
}

// ---------------- routing: logits -> top2 -> softmax ----------------
__global__ void moe_route(const float* __restrict__ hs,
                          const float* __restrict__ wg,
                          int* __restrict__ counts,
                          int* __restrict__ top_idx,
                          float* __restrict__ top_w) {
  const int token = blockIdx.x * 4 + (threadIdx.x >> 6);
  const int lane = threadIdx.x & 63;
  const float* row = hs + (size_t)token * HIDDEN;
  float acc[NEXP];
#pragma unroll
  for (int e = 0; e < NEXP; e++) acc[e] = 0.f;
  for (int j = lane; j < HIDDEN; j += 64) {
    float x = row[j];
#pragma unroll
    for (int e = 0; e < NEXP; e++) acc[e] += x * wg[e * HIDDEN + j];
  }
#pragma unroll
  for (int e = 0; e < NEXP; e++) {
    float v = acc[e];
    for (int off = 32; off > 0; off >>= 1) v += __shfl_down(v, off);
    acc[e] = v;
  }
  if (lane == 0) {
    int i0 = 0; float v0 = acc[0];
#pragma unroll
    for (int e = 1; e < NEXP; e++) if (acc[e] > v0) { v0 = acc[e]; i0 = e; }
    int i1 = -1; float v1 = -3.0e38f;
#pragma unroll
    for (int e = 0; e < NEXP; e++) if (e != i0 && acc[e] > v1) { v1 = acc[e]; i1 = e; }
    float e1 = __expf(v1 - v0);
    float s = 1.f + e1;
    top_idx[token * 2 + 0] = i0;
    top_idx[token * 2 + 1] = i1;
    top_w[token * 2 + 0] = 1.f / s;
    top_w[token * 2 + 1] = e1 / s;
    atomicAdd(&counts[i0], 1);
    atomicAdd(&counts[i1], 1);
  }
}

__global__ void moe_scan(const int* __restrict__ counts,
                         int* __restrict__ offsets, int* __restrict__ cursor) {
  if (threadIdx.x == 0) {
    int s = 0;
    for (int e = 0; e < NEXP; e++) { offsets[e] = s; cursor[e] = s; s += counts[e]; }
  }
}

__global__ void moe_assign(const int* __restrict__ top_idx,
                           const float* __restrict__ top_w,
                           int* __restrict__ cursor,
                           int* __restrict__ token_of,
                           float* __restrict__ wgt_of,
                           int* __restrict__ slot_of) {
  const int t = blockIdx.x * 256 + threadIdx.x;
#pragma unroll
  for (int k = 0; k < 2; k++) {
    int e = top_idx[t * 2 + k];
    int pos = atomicAdd(&cursor[e], 1);
    token_of[pos] = t;
    wgt_of[pos] = top_w[t * 2 + k];
    slot_of[t * 2 + k] = pos;
  }
}

// LDS layout: per 16-row x 32-k block (1024 B): element (row r, 16B-kseg s) at
//   r*64 + ((s ^ ((r>>1)&3)) * 16).
// Staging: DMA forces lane l -> base+16l = (r=l>>2, chunk=l&3); global side
//   fetches kseg s = (l&3)^((l>>3)&3) -> 4-lane groups cover one 64B line
//   (coalesced). Fragment read: lane(l16,quad) -> l16*64 + (quad^((l16>>1)&3))*16;
//   every ALIGNED-4-LANE group (the b128 conflict granule, est. from R1/R2/R3
//   counter data) hits 4 distinct bank-quads for both patterns -> conflict-free.

// ---------------- grouped GEMM A: act = silu(hs@WgT) * (hs@WuT), BK=64 ----------------
__global__ __launch_bounds__(256, 3) void gemm_gateup(
    const unsigned short* __restrict__ hs_bf,
    const unsigned short* __restrict__ wg_bf,
    const unsigned short* __restrict__ wu_bf,
    const int* __restrict__ counts,
    const int* __restrict__ offsets,
    const int* __restrict__ token_of,
    unsigned short* __restrict__ act) {
  const int e = blockIdx.z;
  const int cnt = counts[e];
  const int mbase = blockIdx.y * 128;
  if (mbase >= cnt) return;
  const int off0 = offsets[e];
  const int ntile = blockIdx.x;

  __shared__ __align__(16) unsigned short sA[128 * 64];   // 16 KB
  __shared__ __align__(16) unsigned short sBg[128 * 64];  // 16 KB
  __shared__ __align__(16) unsigned short sBu[128 * 64];  // 16 KB
  __shared__ int rb[128];

  const int tid = threadIdx.x;
  const int wave = tid >> 6;
  const int lane = tid & 63;

  if (tid < 128) {
    int slot = off0 + mbase + tid;
    int last = off0 + cnt - 1;
    if (slot > last) slot = last;
    rb[tid] = token_of[slot] * (HIDDEN * 2);
  }
  __syncthreads();

  const int r = lane >> 2;                      // staging row within 16-row block
  const int colb = ((lane & 3) ^ ((lane >> 3) & 3)) * 16;  // swizzled global kseg
  const int rbk0 = wave;                        // rowblocks staged by this wave
  const int rbk1 = wave + 4;

  const char* pA = (const char*)hs_bf;
  const char* pBg = (const char*)wg_bf + (size_t)e * INTER * HIDDEN * 2;
  const char* pBu = (const char*)wu_bf + (size_t)e * INTER * HIDDEN * 2;
  const long a0 = (long)rb[rbk0 * 16 + r] + colb;
  const long a1 = (long)rb[rbk1 * 16 + r] + colb;
  const long b0 = (long)(ntile * 128 + rbk0 * 16 + r) * (HIDDEN * 2) + colb;
  const long b1 = (long)(ntile * 128 + rbk1 * 16 + r) * (HIDDEN * 2) + colb;

  unsigned short* dA0 = &sA[rbk0 * 1024];
  unsigned short* dA1 = &sA[rbk1 * 1024];
  unsigned short* dBg0 = &sBg[rbk0 * 1024];
  unsigned short* dBg1 = &sBg[rbk1 * 1024];
  unsigned short* dBu0 = &sBu[rbk0 * 1024];
  unsigned short* dBu1 = &sBu[rbk1 * 1024];

  floatx4 accg[4][4], accu[4][4];
  const floatx4 zf = {0.f, 0.f, 0.f, 0.f};
#pragma unroll
  for (int i = 0; i < 4; i++)
#pragma unroll
    for (int j = 0; j < 4; j++) { accg[i][j] = zf; accu[i][j] = zf; }

  const int quad = lane >> 4;
  const int l16 = lane & 15;
  const int wm = (wave >> 1) * 64;
  const int wn = (wave & 1) * 64;
  const int ab = (wave >> 1) * 4;   // A rowblock base for reads
  const int bb = (wave & 1) * 4;    // B rowblock base for reads
  const int frg = l16 * 32 + ((quad ^ ((l16 >> 1) & 3)) * 8);  // ushort idx in 1KB blk

  for (int kk = 0; kk < HIDDEN / 64; kk++) {
    const long kb = kk * 128;
    __syncthreads();
    async16(pA + a0 + kb, dA0);
    async16(pA + a0 + kb + 64, dA0 + 512);
    async16(pA + a1 + kb, dA1);
    async16(pA + a1 + kb + 64, dA1 + 512);
    async16(pBg + b0 + kb, dBg0);
    async16(pBg + b0 + kb + 64, dBg0 + 512);
    async16(pBg + b1 + kb, dBg1);
    async16(pBg + b1 + kb + 64, dBg1 + 512);
    async16(pBu + b0 + kb, dBu0);
    async16(pBu + b0 + kb + 64, dBu0 + 512);
    async16(pBu + b1 + kb, dBu1);
    async16(pBu + b1 + kb + 64, dBu1 + 512);
    __syncthreads();
#pragma unroll
    for (int h = 0; h < 2; h++) {
      bf16x8 a[4], bg[4], bu[4];
#pragma unroll
      for (int i = 0; i < 4; i++) {
        a[i] = *(const bf16x8*)&sA[(ab + i) * 1024 + h * 512 + frg];
        bg[i] = *(const bf16x8*)&sBg[(bb + i) * 1024 + h * 512 + frg];
        bu[i] = *(const bf16x8*)&sBu[(bb + i) * 1024 + h * 512 + frg];
      }
#pragma unroll
      for (int i = 0; i < 4; i++)
#pragma unroll
        for (int j = 0; j < 4; j++) {
          accg[i][j] = __builtin_amdgcn_mfma_f32_16x16x32_bf16(a[i], bg[j], accg[i][j], 0, 0, 0);
          accu[i][j] = __builtin_amdgcn_mfma_f32_16x16x32_bf16(a[i], bu[j], accu[i][j], 0, 0, 0);
        }
    }
  }

  const size_t actrow0 = (size_t)(off0 + mbase);
#pragma unroll
  for (int i = 0; i < 4; i++) {
#pragma unroll
    for (int rr = 0; rr < 4; rr++) {
      const int m = wm + i * 16 + quad * 4 + rr;
      if (mbase + m < cnt) {
        unsigned short* dst = act + (actrow0 + m) * INTER + ntile * 128 + wn + l16;
#pragma unroll
        for (int j = 0; j < 4; j++) {
          float g = accg[i][j][rr];
          float u = accu[i][j][rr];
          float s = g / (1.f + __expf(-g)) * u;
          dst[j * 16] = f2bf(s);
        }
      }
    }
  }
}

// ---------------- grouped GEMM B: slot_out[slot] = w * (act @ WdT), BK=64 ----------------
__global__ __launch_bounds__(256, 3) void gemm_down(
    const unsigned short* __restrict__ act,
    const unsigned short* __restrict__ wd_bf,
    const int* __restrict__ counts,
    const int* __restrict__ offsets,
    const float* __restrict__ wgt_of,
    float* __restrict__ slot_out) {
  const int e = blockIdx.z;
  const int cnt = counts[e];
  const int mbase = blockIdx.y * 128;
  if (mbase >= cnt) return;
  const int off0 = offsets[e];
  const int ntile = blockIdx.x;

  __shared__ __align__(16) unsigned short sA[128 * 64];   // 16 KB
  __shared__ __align__(16) unsigned short sB[128 * 64];   // 16 KB
  __shared__ float wl[128];

  const int tid = threadIdx.x;
  const int wave = tid >> 6;
  const int lane = tid & 63;

  if (tid < 128) {
    int slot = off0 + mbase + tid;
    int last = off0 + cnt - 1;
    if (slot > last) slot = last;
    wl[tid] = wgt_of[slot];
  }
  __syncthreads();

  const int r = lane >> 2;
  const int colb = ((lane & 3) ^ ((lane >> 3) & 3)) * 16;
  const int rbk0 = wave;
  const int rbk1 = wave + 4;

  const int last = off0 + cnt - 1;
  int s0 = off0 + mbase + rbk0 * 16 + r; if (s0 > last) s0 = last;
  int s1 = off0 + mbase + rbk1 * 16 + r; if (s1 > last) s1 = last;
  const char* pA = (const char*)act;
  const char* pB = (const char*)wd_bf + (size_t)e * HIDDEN * INTER * 2;
  const long a0 = (long)s0 * (INTER * 2) + colb;
  const long a1 = (long)s1 * (INTER * 2) + colb;
  const long b0 = (long)(ntile * 128 + rbk0 * 16 + r) * (INTER * 2) + colb;
  const long b1 = (long)(ntile * 128 + rbk1 * 16 + r) * (INTER * 2) + colb;

  unsigned short* dA0 = &sA[rbk0 * 1024];
  unsigned short* dA1 = &sA[rbk1 * 1024];
  unsigned short* dB0 = &sB[rbk0 * 1024];
  unsigned short* dB1 = &sB[rbk1 * 1024];

  floatx4 acc[4][4];
  const floatx4 zf = {0.f, 0.f, 0.f, 0.f};
#pragma unroll
  for (int i = 0; i < 4; i++)
#pragma unroll
    for (int j = 0; j < 4; j++) acc[i][j] = zf;

  const int quad = lane >> 4;
  const int l16 = lane & 15;
  const int wm = (wave >> 1) * 64;
  const int wn = (wave & 1) * 64;
  const int ab = (wave >> 1) * 4;
  const int bb = (wave & 1) * 4;
  const int frg = l16 * 32 + ((quad ^ ((l16 >> 1) & 3)) * 8);

  for (int kk = 0; kk < INTER / 64; kk++) {
    const long kb = kk * 128;
    __syncthreads();
    async16(pA + a0 + kb, dA0);
    async16(pA + a0 + kb + 64, dA0 + 512);
    async16(pA + a1 + kb, dA1);
    async16(pA + a1 + kb + 64, dA1 + 512);
    async16(pB + b0 + kb, dB0);
    async16(pB + b0 + kb + 64, dB0 + 512);
    async16(pB + b1 + kb, dB1);
    async16(pB + b1 + kb + 64, dB1 + 512);
    __syncthreads();
#pragma unroll
    for (int h = 0; h < 2; h++) {
      bf16x8 a[4], b[4];
#pragma unroll
      for (int i = 0; i < 4; i++) {
        a[i] = *(const bf16x8*)&sA[(ab + i) * 1024 + h * 512 + frg];
        b[i] = *(const bf16x8*)&sB[(bb + i) * 1024 + h * 512 + frg];
      }
#pragma unroll
      for (int i = 0; i < 4; i++)
#pragma unroll
        for (int j = 0; j < 4; j++)
          acc[i][j] = __builtin_amdgcn_mfma_f32_16x16x32_bf16(a[i], b[j], acc[i][j], 0, 0, 0);
    }
  }

#pragma unroll
  for (int i = 0; i < 4; i++) {
#pragma unroll
    for (int rr = 0; rr < 4; rr++) {
      const int m = wm + i * 16 + quad * 4 + rr;
      if (mbase + m < cnt) {
        const float w = wl[m];
        float* dst = slot_out + (size_t)(off0 + mbase + m) * HIDDEN + ntile * 128 + wn + l16;
#pragma unroll
        for (int j = 0; j < 4; j++) dst[j * 16] = acc[i][j][rr] * w;
      }
    }
  }
}

// ---------------- combine: out[t] = slot_out[slotA] + slot_out[slotB] ----------------
__global__ void moe_combine(const float* __restrict__ slot_out,
                            const int* __restrict__ slot_of,
                            float* __restrict__ out) {
  const int idx = blockIdx.x * 256 + threadIdx.x;   // TOKENS*256 total
  const int t = idx >> 8;
  const int c4 = idx & 255;
  const int sa = slot_of[t * 2 + 0];
  const int sb = slot_of[t * 2 + 1];
  float4 a = ((const float4*)(slot_out + (size_t)sa * HIDDEN))[c4];
  float4 b = ((const float4*)(slot_out + (size_t)sb * HIDDEN))[c4];
  float4 o;
  o.x = a.x + b.x; o.y = a.y + b.y; o.z = a.z + b.z; o.w = a.w + b.w;
  ((float4*)(out + (size_t)t * HIDDEN))[c4] = o;
}

extern "C" void kernel_launch(void* const* d_in, const int* in_sizes, int n_in,
                              void* d_out, int out_size, void* d_ws, size_t ws_size,
                              hipStream_t stream) {
  const float* hs = (const float*)d_in[0];
  const float* wg = (const float*)d_in[1];
  const float* wgp = (const float*)d_in[2];
  const float* wup = (const float*)d_in[3];
  const float* wdp = (const float*)d_in[4];
  float* out = (float*)d_out;

  char* ws = (char*)d_ws;
  int* counts = (int*)(ws + 0);
  int* cursor = (int*)(ws + 256);
  int* offsets = (int*)(ws + 512);
  int* top_idx = (int*)(ws + 1024);
  float* top_w = (float*)(ws + 1024 + 65536);
  int* token_of = (int*)(ws + 1024 + 2 * 65536);
  float* wgt_of = (float*)(ws + 1024 + 3 * 65536);
  int* slot_of = (int*)(ws + 1024 + 4 * 65536);
  size_t base = 1024 + 5 * 65536;
  unsigned short* hs_bf = (unsigned short*)(ws + base);
  base += (size_t)TOKENS * HIDDEN * 2;
  unsigned short* wg_bf = (unsigned short*)(ws + base);
  base += (size_t)NEXP * INTER * HIDDEN * 2;
  unsigned short* wu_bf = (unsigned short*)(ws + base);
  base += (size_t)NEXP * INTER * HIDDEN * 2;
  unsigned short* wd_bf = (unsigned short*)(ws + base);
  base += (size_t)NEXP * HIDDEN * INTER * 2;
  unsigned short* act = (unsigned short*)(ws + base);
  // slot_out aliases wg_bf/wu_bf (dead after gemm_gateup): 67.1 MB <= 92.3 MB
  float* slot_out = (float*)wg_bf;

  hipMemsetAsync(d_ws, 0, 768, stream);

  cvt_bf16_4<<<dim3(2048, 1, 4), 256, 0, stream>>>(
      hs, hs_bf, TOKENS * HIDDEN / 4,
      wgp, wg_bf, NEXP * INTER * HIDDEN / 4,
      wup, wu_bf, NEXP * INTER * HIDDEN / 4,
      wdp, wd_bf, NEXP * HIDDEN * INTER / 4);

  moe_route<<<TOKENS / 4, 256, 0, stream>>>(hs, wg, counts, top_idx, top_w);
  moe_scan<<<1, 64, 0, stream>>>(counts, offsets, cursor);
  moe_assign<<<TOKENS / 256, 256, 0, stream>>>(top_idx, top_w, cursor, token_of, wgt_of, slot_of);

  dim3 g1(INTER / 128, TOKENS / 128, NEXP);
  gemm_gateup<<<g1, 256, 0, stream>>>(hs_bf, wg_bf, wu_bf, counts, offsets, token_of, act);
  dim3 g2(HIDDEN / 128, TOKENS / 128, NEXP);
  gemm_down<<<g2, 256, 0, stream>>>(act, wd_bf, counts, offsets, wgt_of, slot_out);
  moe_combine<<<TOKENS, 256, 0, stream>>>(slot_out, slot_of, out);
}